// Round 3
// baseline (24941.780 us; speedup 1.0000x reference)
//
#include <hip/hip_runtime.h>
#include <hip/hip_bf16.h>
#include <hip/hip_cooperative_groups.h>
#include <math.h>

namespace cg = cooperative_groups;

#define SEQ_LEN 512
#define IN_SZ   4096
#define HID     2048
#define OUT_SZ  4096
#define G3      (3*HID)      // 6144
#define STEPS   30

// ---------------------------------------------------------------------------
// K0: Gi[t][r] = sum_k input[t][k] * enc_Wih[r][k] + enc_bih[r]
// ---------------------------------------------------------------------------
#define BM 64
#define BN 64
#define BK 16
__global__ __launch_bounds__(256) void gemm_gi(
    const float* __restrict__ A, const float* __restrict__ B,
    const float* __restrict__ bias, float* __restrict__ C) {
  __shared__ float As[BK][BM];
  __shared__ float Bs[BK][BN];
  const int tid = threadIdx.x;
  const int m0 = blockIdx.x * BM;
  const int n0 = blockIdx.y * BN;
  const int tx = tid & 15, ty = tid >> 4;
  float acc[4][4] = {};
  for (int k0 = 0; k0 < IN_SZ; k0 += BK) {
#pragma unroll
    for (int i = 0; i < 4; i++) {
      int idx = tid + i * 256;
      int r = idx >> 4, k = idx & 15;
      As[k][r] = A[(size_t)(m0 + r) * IN_SZ + k0 + k];
      Bs[k][r] = B[(size_t)(n0 + r) * IN_SZ + k0 + k];
    }
    __syncthreads();
#pragma unroll
    for (int k = 0; k < BK; k++) {
      float a[4], b[4];
#pragma unroll
      for (int i = 0; i < 4; i++) { a[i] = As[k][ty * 4 + i]; b[i] = Bs[k][tx * 4 + i]; }
#pragma unroll
      for (int i = 0; i < 4; i++)
#pragma unroll
        for (int j = 0; j < 4; j++) acc[i][j] += a[i] * b[j];
    }
    __syncthreads();
  }
#pragma unroll
  for (int i = 0; i < 4; i++)
#pragma unroll
    for (int j = 0; j < 4; j++) {
      int m = m0 + ty * 4 + i, n = n0 + tx * 4 + j;
      C[(size_t)m * G3 + n] = acc[i][j] + bias[n];
    }
}

__device__ __forceinline__ float wave_reduce(float v) {
#pragma unroll
  for (int off = 32; off > 0; off >>= 1) v += __shfl_down(v, off, 64);
  return v;
}

// ---------------------------------------------------------------------------
// K1: persistent cooperative encoder. 256 blocks x 512 thr (8 waves), exactly
// 1 block/CU (__launch_bounds__(512,2): 2 waves/EU, VGPR cap 256). Wave w of
// block b owns j = 8b + w; Whh rows j, H+j, 2H+j live in registers (96 VGPRs)
// for all 512 steps. h ping-pong crosses XCDs, so ALL h traffic uses
// agent-scope atomics (sc1 -> MALL coherence point); plain loads/stores +
// fences proved insufficient in round 2 (stale per-XCD L2, absmax 0.875).
// ---------------------------------------------------------------------------
__global__ __launch_bounds__(512, 2) void enc_persistent(
    const float* __restrict__ Gi,       // SEQ_LEN x G3 (bih already added)
    const float* __restrict__ Whh,      // G3 x HID
    const float* __restrict__ bhh,
    float* __restrict__ hbuf0,          // ping (h0 = 0 pre-set)
    float* __restrict__ hbuf1) {        // pong
  cg::grid_group grid = cg::this_grid();
  const int tid = threadIdx.x;
  const int wave = tid >> 6, lane = tid & 63;
  const int j = blockIdx.x * 8 + wave;

  float4 w[3][8];
#pragma unroll
  for (int g = 0; g < 3; g++) {
    const float4* wp = (const float4*)(Whh + (size_t)(g * HID + j) * HID);
#pragma unroll
    for (int i = 0; i < 8; i++) w[g][i] = wp[lane + i * 64];
  }
  const float b0 = bhh[j], b1 = bhh[j + HID], b2 = bhh[j + 2 * HID];

  for (int t = 0; t < SEQ_LEN; t++) {
    const float* hs = (t & 1) ? hbuf1 : hbuf0;
    float*       hd = (t & 1) ? hbuf0 : hbuf1;
    const double* h8 = (const double*)hs;
    float a0 = 0.f, a1 = 0.f, a2 = 0.f;
#pragma unroll
    for (int i = 0; i < 8; i++) {
      const int base = (lane + i * 64) * 2;
      double d0 = __hip_atomic_load(h8 + base,     __ATOMIC_RELAXED, __HIP_MEMORY_SCOPE_AGENT);
      double d1 = __hip_atomic_load(h8 + base + 1, __ATOMIC_RELAXED, __HIP_MEMORY_SCOPE_AGENT);
      float2 f0 = __builtin_bit_cast(float2, d0);
      float2 f1 = __builtin_bit_cast(float2, d1);
      // same accumulation order as round 1 (x,y,z,w of each float4)
      a0 += w[0][i].x * f0.x + w[0][i].y * f0.y + w[0][i].z * f1.x + w[0][i].w * f1.y;
      a1 += w[1][i].x * f0.x + w[1][i].y * f0.y + w[1][i].z * f1.x + w[1][i].w * f1.y;
      a2 += w[2][i].x * f0.x + w[2][i].y * f0.y + w[2][i].z * f1.x + w[2][i].w * f1.y;
    }
    a0 = wave_reduce(a0);
    a1 = wave_reduce(a1);
    a2 = wave_reduce(a2);
    if (lane == 0) {
      float hold = __hip_atomic_load(hs + j, __ATOMIC_RELAXED, __HIP_MEMORY_SCOPE_AGENT);
      const float* gi = Gi + (size_t)t * G3;
      float r = 1.f / (1.f + expf(-(gi[j] + a0 + b0)));
      float z = 1.f / (1.f + expf(-(gi[j + HID] + a1 + b1)));
      float n = tanhf(gi[j + 2 * HID] + r * (a2 + b2));
      __hip_atomic_store(hd + j, (1.f - z) * n + z * hold,
                         __ATOMIC_RELEASE, __HIP_MEMORY_SCOPE_AGENT);
    }
    grid.sync();
  }
}

// ---------------------------------------------------------------------------
// K1-fallback: one encoder GRU step (round-1 kernel, known correct).
// ---------------------------------------------------------------------------
__global__ __launch_bounds__(256) void enc_step(
    const float* __restrict__ gi_row,
    const float* __restrict__ h_old,
    const float* __restrict__ Whh,
    const float* __restrict__ bhh,
    float* __restrict__ h_new) {
  __shared__ float hsh[HID];
  const int tid = threadIdx.x;
#pragma unroll
  for (int i = 0; i < HID / 256; i++) hsh[tid + i * 256] = h_old[tid + i * 256];
  __syncthreads();
  const int wave = tid >> 6, lane = tid & 63;
  const int j = blockIdx.x * 4 + wave;
  const float4* hs4 = (const float4*)hsh;
  float dots[3];
#pragma unroll
  for (int g = 0; g < 3; g++) {
    const float4* wp = (const float4*)(Whh + (size_t)(g * HID + j) * HID);
    float acc = 0.f;
#pragma unroll
    for (int i = 0; i < 8; i++) {
      float4 w = wp[lane + i * 64];
      float4 h = hs4[lane + i * 64];
      acc += w.x * h.x + w.y * h.y + w.z * h.z + w.w * h.w;
    }
    dots[g] = wave_reduce(acc);
  }
  if (lane == 0) {
    float gr = dots[0] + bhh[j];
    float gz = dots[1] + bhh[j + HID];
    float gn = dots[2] + bhh[j + 2 * HID];
    float ir = gi_row[j], iz = gi_row[j + HID], in = gi_row[j + 2 * HID];
    float r = 1.f / (1.f + expf(-(ir + gr)));
    float z = 1.f / (1.f + expf(-(iz + gz)));
    float n = tanhf(in + r * gn);
    h_new[j] = (1.f - z) * n + z * hsh[j];
  }
}

// ---------------------------------------------------------------------------
// K2: one decoder GRU step (unchanged, known correct).
// ---------------------------------------------------------------------------
__global__ __launch_bounds__(256) void dec_step(
    const float* __restrict__ Wih,
    const float* __restrict__ bih,
    const int* __restrict__ idxp, int has_idx,
    const float* __restrict__ h_old,
    const float* __restrict__ Whh,
    const float* __restrict__ bhh,
    float* __restrict__ h_new) {
  __shared__ float hsh[HID];
  const int tid = threadIdx.x;
#pragma unroll
  for (int i = 0; i < HID / 256; i++) hsh[tid + i * 256] = h_old[tid + i * 256];
  __syncthreads();
  const int wave = tid >> 6, lane = tid & 63;
  const int j = blockIdx.x * 4 + wave;
  const float4* hs4 = (const float4*)hsh;
  float dots[3];
#pragma unroll
  for (int g = 0; g < 3; g++) {
    const float4* wp = (const float4*)(Whh + (size_t)(g * HID + j) * HID);
    float acc = 0.f;
#pragma unroll
    for (int i = 0; i < 8; i++) {
      float4 w = wp[lane + i * 64];
      float4 h = hs4[lane + i * 64];
      acc += w.x * h.x + w.y * h.y + w.z * h.z + w.w * h.w;
    }
    dots[g] = wave_reduce(acc);
  }
  if (lane == 0) {
    int idx = has_idx ? *idxp : 0;
    float gi[3];
#pragma unroll
    for (int g = 0; g < 3; g++) {
      int row = g * HID + j;
      float v = bih[row];
      if (has_idx) v += Wih[(size_t)row * OUT_SZ + idx];
      gi[g] = v;
    }
    float gr = dots[0] + bhh[j];
    float gz = dots[1] + bhh[j + HID];
    float gn = dots[2] + bhh[j + 2 * HID];
    float r = 1.f / (1.f + expf(-(gi[0] + gr)));
    float z = 1.f / (1.f + expf(-(gi[1] + gz)));
    float n = tanhf(gi[2] + r * gn);
    h_new[j] = (1.f - z) * n + z * hsh[j];
  }
}

// ---------------------------------------------------------------------------
// K3: logits (unchanged)
// ---------------------------------------------------------------------------
__global__ __launch_bounds__(256) void logits_kernel(
    const float* __restrict__ W, const float* __restrict__ b,
    const float* __restrict__ h, float* __restrict__ logits) {
  __shared__ float hsh[HID];
  const int tid = threadIdx.x;
#pragma unroll
  for (int i = 0; i < HID / 256; i++) hsh[tid + i * 256] = h[tid + i * 256];
  __syncthreads();
  const int wave = tid >> 6, lane = tid & 63;
  const int row = blockIdx.x * 4 + wave;
  const float4* hs4 = (const float4*)hsh;
  const float4* wp = (const float4*)(W + (size_t)row * HID);
  float acc = 0.f;
#pragma unroll
  for (int i = 0; i < 8; i++) {
    float4 w = wp[lane + i * 64];
    float4 hv = hs4[lane + i * 64];
    acc += w.x * hv.x + w.y * hv.y + w.z * hv.z + w.w * hv.w;
  }
  acc = wave_reduce(acc);
  if (lane == 0) logits[row] = acc + b[row];
}

// ---------------------------------------------------------------------------
// K4: log_softmax + argmax (unchanged)
// ---------------------------------------------------------------------------
__global__ __launch_bounds__(256) void softmax_kernel(
    const float* __restrict__ logits, float* __restrict__ out_row,
    int* __restrict__ idx_out) {
  __shared__ float sval[256];
  __shared__ int sidx[256];
  const int tid = threadIdx.x;
  float best = -INFINITY; int bidx = 0x7fffffff;
  for (int i = tid; i < OUT_SZ; i += 256) {
    float v = logits[i];
    if (v > best) { best = v; bidx = i; }
  }
  sval[tid] = best; sidx[tid] = bidx;
  __syncthreads();
  for (int s = 128; s > 0; s >>= 1) {
    if (tid < s) {
      float v2 = sval[tid + s]; int i2 = sidx[tid + s];
      if (v2 > sval[tid] || (v2 == sval[tid] && i2 < sidx[tid])) {
        sval[tid] = v2; sidx[tid] = i2;
      }
    }
    __syncthreads();
  }
  const float m = sval[0];
  const int amax = sidx[0];
  __syncthreads();
  float lsum = 0.f;
  for (int i = tid; i < OUT_SZ; i += 256) lsum += expf(logits[i] - m);
  sval[tid] = lsum;
  __syncthreads();
  for (int s = 128; s > 0; s >>= 1) {
    if (tid < s) sval[tid] += sval[tid + s];
    __syncthreads();
  }
  const float ls = logf(sval[0]);
  for (int i = tid; i < OUT_SZ; i += 256) out_row[i] = logits[i] - m - ls;
  if (tid == 0) *idx_out = amax;
}

// ---------------------------------------------------------------------------
extern "C" void kernel_launch(void* const* d_in, const int* in_sizes, int n_in,
                              void* d_out, int out_size, void* d_ws, size_t ws_size,
                              hipStream_t stream) {
  const float* input   = (const float*)d_in[0];
  const float* enc_Wih = (const float*)d_in[1];
  const float* enc_Whh = (const float*)d_in[2];
  const float* enc_bih = (const float*)d_in[3];
  const float* enc_bhh = (const float*)d_in[4];
  const float* dec_Wih = (const float*)d_in[5];
  const float* dec_Whh = (const float*)d_in[6];
  const float* dec_bih = (const float*)d_in[7];
  const float* dec_bhh = (const float*)d_in[8];
  const float* W_out   = (const float*)d_in[9];
  const float* b_out   = (const float*)d_in[10];
  float* out = (float*)d_out;

  float* ws = (float*)d_ws;
  float* Gi     = ws;                                   // 512*6144
  float* ha     = ws + (size_t)SEQ_LEN * G3;            // 2048
  float* hb     = ha + HID;                             // 2048
  float* logits = hb + HID;                             // 4096
  int*   idxp   = (int*)(logits + OUT_SZ);              // 1

  hipMemsetAsync(ha, 0, HID * sizeof(float), stream);   // h0 = 0

  dim3 g0(SEQ_LEN / BM, G3 / BN);
  gemm_gi<<<g0, 256, 0, stream>>>(input, enc_Wih, enc_bih, Gi);

  {
    void* args[] = {(void*)&Gi, (void*)&enc_Whh, (void*)&enc_bhh,
                    (void*)&ha, (void*)&hb};
    hipError_t err = hipLaunchCooperativeKernel((void*)enc_persistent,
                                                dim3(256), dim3(512),
                                                args, 0, stream);
    if (err != hipSuccess) {
      // deterministic fallback: round-1 multi-launch encoder
      float* hin = ha; float* hout = hb;
      for (int t = 0; t < SEQ_LEN; t++) {
        enc_step<<<HID / 4, 256, 0, stream>>>(Gi + (size_t)t * G3, hin, enc_Whh,
                                              enc_bhh, hout);
        float* tmp = hin; hin = hout; hout = tmp;
      }
    }
  }
  // 512 steps (even) -> h_enc lands in ha on both paths.

  float* hin = ha; float* hout = hb;
  for (int s = 0; s < STEPS; s++) {
    dec_step<<<HID / 4, 256, 0, stream>>>(dec_Wih, dec_bih, idxp, s == 0 ? 0 : 1,
                                          hin, dec_Whh, dec_bhh, hout);
    logits_kernel<<<OUT_SZ / 4, 256, 0, stream>>>(W_out, b_out, hout, logits);
    softmax_kernel<<<1, 256, 0, stream>>>(logits, out + (size_t)s * OUT_SZ, idxp);
    float* tmp = hin; hin = hout; hout = tmp;
  }
}

// Round 4
// 3767.124 us; speedup vs baseline: 6.6209x; 6.6209x over previous
//
#include <hip/hip_runtime.h>
#include <hip/hip_bf16.h>
#include <math.h>

#define SEQ_LEN 512
#define IN_SZ   4096
#define HID     2048
#define OUT_SZ  4096
#define G3      (3*HID)      // 6144
#define STEPS   30

// ---------------------------------------------------------------------------
// Kc: fp32 -> bf16 (RNE) conversion, float4/ushort4 vectorized, grid-stride.
// ---------------------------------------------------------------------------
__device__ __forceinline__ unsigned short f2bf(float f) {
  unsigned int u = __float_as_uint(f);
  unsigned int r = (u + 0x7fffu + ((u >> 16) & 1u)) >> 16;
  return (unsigned short)r;
}

__global__ __launch_bounds__(256) void conv_bf16(
    const float* __restrict__ src, unsigned short* __restrict__ dst, int n4) {
  int i = blockIdx.x * blockDim.x + threadIdx.x;
  const int stride = gridDim.x * blockDim.x;
  const float4* s4 = (const float4*)src;
  ushort4* d4 = (ushort4*)dst;
  for (; i < n4; i += stride) {
    float4 v = s4[i];
    ushort4 o;
    o.x = f2bf(v.x); o.y = f2bf(v.y); o.z = f2bf(v.z); o.w = f2bf(v.w);
    d4[i] = o;
  }
}

// ---------------------------------------------------------------------------
// K0: Gi[t][r] = sum_k input[t][k] * enc_Wih[r][k] + enc_bih[r]   (fp32)
// ---------------------------------------------------------------------------
#define BM 64
#define BN 64
#define BK 16
__global__ __launch_bounds__(256) void gemm_gi(
    const float* __restrict__ A, const float* __restrict__ B,
    const float* __restrict__ bias, float* __restrict__ C) {
  __shared__ float As[BK][BM];
  __shared__ float Bs[BK][BN];
  const int tid = threadIdx.x;
  const int m0 = blockIdx.x * BM;
  const int n0 = blockIdx.y * BN;
  const int tx = tid & 15, ty = tid >> 4;
  float acc[4][4] = {};
  for (int k0 = 0; k0 < IN_SZ; k0 += BK) {
#pragma unroll
    for (int i = 0; i < 4; i++) {
      int idx = tid + i * 256;
      int r = idx >> 4, k = idx & 15;
      As[k][r] = A[(size_t)(m0 + r) * IN_SZ + k0 + k];
      Bs[k][r] = B[(size_t)(n0 + r) * IN_SZ + k0 + k];
    }
    __syncthreads();
#pragma unroll
    for (int k = 0; k < BK; k++) {
      float a[4], b[4];
#pragma unroll
      for (int i = 0; i < 4; i++) { a[i] = As[k][ty * 4 + i]; b[i] = Bs[k][tx * 4 + i]; }
#pragma unroll
      for (int i = 0; i < 4; i++)
#pragma unroll
        for (int j = 0; j < 4; j++) acc[i][j] += a[i] * b[j];
    }
    __syncthreads();
  }
#pragma unroll
  for (int i = 0; i < 4; i++)
#pragma unroll
    for (int j = 0; j < 4; j++) {
      int m = m0 + ty * 4 + i, n = n0 + tx * 4 + j;
      C[(size_t)m * G3 + n] = acc[i][j] + bias[n];
    }
}

__device__ __forceinline__ float wave_reduce(float v) {
#pragma unroll
  for (int off = 32; off > 0; off >>= 1) v += __shfl_down(v, off, 64);
  return v;
}

// 8 bf16 (uint4) dot 8 fp32 (two float4 from LDS), fp32 accumulate.
__device__ __forceinline__ float dot8_bf(uint4 wv, float4 h0, float4 h1) {
  float w0 = __uint_as_float(wv.x << 16);
  float w1 = __uint_as_float(wv.x & 0xffff0000u);
  float w2 = __uint_as_float(wv.y << 16);
  float w3 = __uint_as_float(wv.y & 0xffff0000u);
  float w4 = __uint_as_float(wv.z << 16);
  float w5 = __uint_as_float(wv.z & 0xffff0000u);
  float w6 = __uint_as_float(wv.w << 16);
  float w7 = __uint_as_float(wv.w & 0xffff0000u);
  return w0 * h0.x + w1 * h0.y + w2 * h0.z + w3 * h0.w +
         w4 * h1.x + w5 * h1.y + w6 * h1.z + w7 * h1.w;
}

// ---------------------------------------------------------------------------
// K1: one encoder GRU step, bf16 weights. Block = 256 thr (4 waves), wave w
// owns h-index j = 4b + w (rows j, H+j, 2H+j). Per wave-row: 2048 bf16 =
// 4 KB = 4 x uint4 per lane. h (fp32) staged in LDS. Grid = 512 blocks.
// bf16 Whh = 25 MB -> ~3.1 MB/XCD slice, L2-resident across launches.
// ---------------------------------------------------------------------------
__global__ __launch_bounds__(256) void enc_step_bf(
    const float* __restrict__ gi_row,
    const float* __restrict__ h_old,
    const unsigned short* __restrict__ Whh,   // bf16, G3 x HID
    const float* __restrict__ bhh,
    float* __restrict__ h_new) {
  __shared__ float hsh[HID];
  const int tid = threadIdx.x;
#pragma unroll
  for (int i = 0; i < HID / 256; i++) hsh[tid + i * 256] = h_old[tid + i * 256];
  __syncthreads();
  const int wave = tid >> 6, lane = tid & 63;
  const int j = blockIdx.x * 4 + wave;
  const float4* hs4 = (const float4*)hsh;
  float dots[3];
#pragma unroll
  for (int g = 0; g < 3; g++) {
    const uint4* wp = (const uint4*)(Whh + (size_t)(g * HID + j) * HID);
    float acc = 0.f;
#pragma unroll
    for (int i = 0; i < 4; i++) {
      uint4 wv = wp[lane + i * 64];
      float4 h0 = hs4[2 * (lane + i * 64)];
      float4 h1 = hs4[2 * (lane + i * 64) + 1];
      acc += dot8_bf(wv, h0, h1);
    }
    dots[g] = wave_reduce(acc);
  }
  if (lane == 0) {
    float gr = dots[0] + bhh[j];
    float gz = dots[1] + bhh[j + HID];
    float gn = dots[2] + bhh[j + 2 * HID];
    float ir = gi_row[j], iz = gi_row[j + HID], in = gi_row[j + 2 * HID];
    float r = 1.f / (1.f + expf(-(ir + gr)));
    float z = 1.f / (1.f + expf(-(iz + gz)));
    float n = tanhf(in + r * gn);
    h_new[j] = (1.f - z) * n + z * hsh[j];
  }
}

// ---------------------------------------------------------------------------
// K2: one decoder GRU step, bf16 Whh. gi = dec_Wih[:, idx] + dec_bih
// (one-hot x); dec_Wih column gather stays fp32 (only 3 scalars/wave).
// ---------------------------------------------------------------------------
__global__ __launch_bounds__(256) void dec_step_bf(
    const float* __restrict__ Wih,            // fp32, G3 x OUT_SZ
    const float* __restrict__ bih,
    const int* __restrict__ idxp, int has_idx,
    const float* __restrict__ h_old,
    const unsigned short* __restrict__ Whh,   // bf16, G3 x HID
    const float* __restrict__ bhh,
    float* __restrict__ h_new) {
  __shared__ float hsh[HID];
  const int tid = threadIdx.x;
#pragma unroll
  for (int i = 0; i < HID / 256; i++) hsh[tid + i * 256] = h_old[tid + i * 256];
  __syncthreads();
  const int wave = tid >> 6, lane = tid & 63;
  const int j = blockIdx.x * 4 + wave;
  const float4* hs4 = (const float4*)hsh;
  float dots[3];
#pragma unroll
  for (int g = 0; g < 3; g++) {
    const uint4* wp = (const uint4*)(Whh + (size_t)(g * HID + j) * HID);
    float acc = 0.f;
#pragma unroll
    for (int i = 0; i < 4; i++) {
      uint4 wv = wp[lane + i * 64];
      float4 h0 = hs4[2 * (lane + i * 64)];
      float4 h1 = hs4[2 * (lane + i * 64) + 1];
      acc += dot8_bf(wv, h0, h1);
    }
    dots[g] = wave_reduce(acc);
  }
  if (lane == 0) {
    int idx = has_idx ? *idxp : 0;
    float gi[3];
#pragma unroll
    for (int g = 0; g < 3; g++) {
      int row = g * HID + j;
      float v = bih[row];
      if (has_idx) v += Wih[(size_t)row * OUT_SZ + idx];
      gi[g] = v;
    }
    float gr = dots[0] + bhh[j];
    float gz = dots[1] + bhh[j + HID];
    float gn = dots[2] + bhh[j + 2 * HID];
    float r = 1.f / (1.f + expf(-(gi[0] + gr)));
    float z = 1.f / (1.f + expf(-(gi[1] + gz)));
    float n = tanhf(gi[2] + r * gn);
    h_new[j] = (1.f - z) * n + z * hsh[j];
  }
}

// ---------------------------------------------------------------------------
// K3: logits[r] = W_out[r,:] . h + b_out[r], bf16 W_out.
// ---------------------------------------------------------------------------
__global__ __launch_bounds__(256) void logits_bf(
    const unsigned short* __restrict__ W,     // bf16, OUT_SZ x HID
    const float* __restrict__ b,
    const float* __restrict__ h, float* __restrict__ logits) {
  __shared__ float hsh[HID];
  const int tid = threadIdx.x;
#pragma unroll
  for (int i = 0; i < HID / 256; i++) hsh[tid + i * 256] = h[tid + i * 256];
  __syncthreads();
  const int wave = tid >> 6, lane = tid & 63;
  const int row = blockIdx.x * 4 + wave;
  const float4* hs4 = (const float4*)hsh;
  const uint4* wp = (const uint4*)(W + (size_t)row * HID);
  float acc = 0.f;
#pragma unroll
  for (int i = 0; i < 4; i++) {
    uint4 wv = wp[lane + i * 64];
    float4 h0 = hs4[2 * (lane + i * 64)];
    float4 h1 = hs4[2 * (lane + i * 64) + 1];
    acc += dot8_bf(wv, h0, h1);
  }
  acc = wave_reduce(acc);
  if (lane == 0) logits[row] = acc + b[row];
}

// ---------------------------------------------------------------------------
// K4: log_softmax + argmax (unchanged, fp32 logits)
// ---------------------------------------------------------------------------
__global__ __launch_bounds__(256) void softmax_kernel(
    const float* __restrict__ logits, float* __restrict__ out_row,
    int* __restrict__ idx_out) {
  __shared__ float sval[256];
  __shared__ int sidx[256];
  const int tid = threadIdx.x;
  float best = -INFINITY; int bidx = 0x7fffffff;
  for (int i = tid; i < OUT_SZ; i += 256) {
    float v = logits[i];
    if (v > best) { best = v; bidx = i; }
  }
  sval[tid] = best; sidx[tid] = bidx;
  __syncthreads();
  for (int s = 128; s > 0; s >>= 1) {
    if (tid < s) {
      float v2 = sval[tid + s]; int i2 = sidx[tid + s];
      if (v2 > sval[tid] || (v2 == sval[tid] && i2 < sidx[tid])) {
        sval[tid] = v2; sidx[tid] = i2;
      }
    }
    __syncthreads();
  }
  const float m = sval[0];
  const int amax = sidx[0];
  __syncthreads();
  float lsum = 0.f;
  for (int i = tid; i < OUT_SZ; i += 256) lsum += expf(logits[i] - m);
  sval[tid] = lsum;
  __syncthreads();
  for (int s = 128; s > 0; s >>= 1) {
    if (tid < s) sval[tid] += sval[tid + s];
    __syncthreads();
  }
  const float ls = logf(sval[0]);
  for (int i = tid; i < OUT_SZ; i += 256) out_row[i] = logits[i] - m - ls;
  if (tid == 0) *idx_out = amax;
}

// ---------------------------------------------------------------------------
extern "C" void kernel_launch(void* const* d_in, const int* in_sizes, int n_in,
                              void* d_out, int out_size, void* d_ws, size_t ws_size,
                              hipStream_t stream) {
  const float* input   = (const float*)d_in[0];
  const float* enc_Wih = (const float*)d_in[1];
  const float* enc_Whh = (const float*)d_in[2];
  const float* enc_bih = (const float*)d_in[3];
  const float* enc_bhh = (const float*)d_in[4];
  const float* dec_Wih = (const float*)d_in[5];
  const float* dec_Whh = (const float*)d_in[6];
  const float* dec_bih = (const float*)d_in[7];
  const float* dec_bhh = (const float*)d_in[8];
  const float* W_out   = (const float*)d_in[9];
  const float* b_out   = (const float*)d_in[10];
  float* out = (float*)d_out;

  float* ws = (float*)d_ws;
  float* Gi     = ws;                                   // 512*6144 fp32
  float* ha     = ws + (size_t)SEQ_LEN * G3;            // 2048
  float* hb     = ha + HID;                             // 2048
  float* logits = hb + HID;                             // 4096
  int*   idxp   = (int*)(logits + OUT_SZ);              // 1
  // bf16 weight copies (16B-aligned by construction)
  unsigned short* encWhh_bf = (unsigned short*)(idxp + 3);          // 12.58M
  unsigned short* decWhh_bf = encWhh_bf + (size_t)G3 * HID;         // 12.58M
  unsigned short* Wout_bf   = decWhh_bf + (size_t)G3 * HID;         // 8.39M

  hipMemsetAsync(ha, 0, HID * sizeof(float), stream);   // h0 = 0

  conv_bf16<<<2048, 256, 0, stream>>>(enc_Whh, encWhh_bf, (G3 * HID) / 4);
  conv_bf16<<<2048, 256, 0, stream>>>(dec_Whh, decWhh_bf, (G3 * HID) / 4);
  conv_bf16<<<2048, 256, 0, stream>>>(W_out,   Wout_bf,   (OUT_SZ * HID) / 4);

  dim3 g0(SEQ_LEN / BM, G3 / BN);
  gemm_gi<<<g0, 256, 0, stream>>>(input, enc_Wih, enc_bih, Gi);

  float* hin = ha; float* hout = hb;
  for (int t = 0; t < SEQ_LEN; t++) {
    enc_step_bf<<<HID / 4, 256, 0, stream>>>(Gi + (size_t)t * G3, hin, encWhh_bf,
                                             enc_bhh, hout);
    float* tmp = hin; hin = hout; hout = tmp;
  }
  // h_enc now in hin (512 steps even -> ha)
  for (int s = 0; s < STEPS; s++) {
    dec_step_bf<<<HID / 4, 256, 0, stream>>>(dec_Wih, dec_bih, idxp, s == 0 ? 0 : 1,
                                             hin, decWhh_bf, dec_bhh, hout);
    logits_bf<<<OUT_SZ / 4, 256, 0, stream>>>(Wout_bf, b_out, hout, logits);
    softmax_kernel<<<1, 256, 0, stream>>>(logits, out + (size_t)s * OUT_SZ, idxp);
    float* tmp = hin; hin = hout; hout = tmp;
  }
}